// Round 10
// baseline (1883.302 us; speedup 1.0000x reference)
//
#include <hip/hip_runtime.h>
#include <hip/hip_bf16.h>

#define N_GRAPHS 64
#define TPAD 68     // padded LDS row stride (floats)
#define NT 16       // src tiles (src >> TSHIFT); tiles 13-15 empty for N=100k
#define TSHIFT 13   // 8192 nodes/tile -> 2MB gather slice per phase
#define NBK 200     // dst nodes per bucket -> 500 buckets
#define NPW 25      // nodes (slots) per wave; 8 waves per bucket
#define NKEY 3200   // keys per bucket: wl*400 + tile*25 + slot
#define NKEYP 3328  // padded to 13*256

// ---------------- bucket-level histogram (bucket = dst/200) ----------------

#define EBH 8192
__global__ void bucket_hist_kernel(const int* __restrict__ dst, int* __restrict__ bcnt,
                                   int E, int nbuck) {
    __shared__ int lh[512];
    const int tid = threadIdx.x;
    for (int i = tid; i < 512; i += 256) lh[i] = 0;
    __syncthreads();
    const int e0 = blockIdx.x * EBH;
    const int e1 = min(e0 + EBH, E);
    for (int e = e0 + tid; e < e1; e += 256)
        atomicAdd(&lh[dst[e] / NBK], 1);
    __syncthreads();
    for (int i = tid; i < nbuck; i += 256) {
        int c = lh[i];
        if (c) atomicAdd(&bcnt[i], c);
    }
}

__global__ void bucket_scan_kernel(const int* __restrict__ bcnt, int* __restrict__ bbase,
                                   int* __restrict__ bcur, int nbuck) {
    __shared__ int sh[512];
    const int tid = threadIdx.x;
    int v = (tid < nbuck) ? bcnt[tid] : 0;
    sh[tid] = v;
    __syncthreads();
    for (int off = 1; off < 512; off <<= 1) {
        int t = (tid >= off) ? sh[tid - off] : 0;
        __syncthreads();
        sh[tid] += t;
        __syncthreads();
    }
    if (tid < nbuck) { int e = sh[tid] - v; bbase[tid] = e; bcur[tid] = e; }
    if (tid == nbuck - 1) bbase[nbuck] = sh[tid];
}

// ---------------- binned scatter: packed edge = dloc<<24 | src ----------------

#define EBC 4096
__global__ void binscatter_kernel(const int* __restrict__ src, const int* __restrict__ dst,
                                  int* __restrict__ bcur, unsigned* __restrict__ binned,
                                  int E, int nbuck) {
    __shared__ int lhist[512];
    __shared__ int lbase[512];
    const int tid = threadIdx.x;
    const int e0 = blockIdx.x * EBC;
    const int e1 = min(e0 + EBC, E);
    for (int i = tid; i < 512; i += 256) lhist[i] = 0;
    __syncthreads();
    for (int e = e0 + tid; e < e1; e += 256) atomicAdd(&lhist[dst[e] / NBK], 1);
    __syncthreads();
    for (int i = tid; i < nbuck; i += 256) {
        int c = lhist[i];
        lbase[i] = (c > 0) ? atomicAdd(&bcur[i], c) : 0;
        lhist[i] = 0;
    }
    __syncthreads();
    for (int e = e0 + tid; e < e1; e += 256) {
        int d = dst[e];
        int b = d / NBK;
        int off = atomicAdd(&lhist[b], 1);
        binned[lbase[b] + off] = ((unsigned)(d - b * NBK) << 24) | (unsigned)src[e];
    }
}

// ---------------- per-bucket build: (wave,tile,slot)-sorted col3 (slot<<24|src),
//                  per-(wave,tile) cnt16, per-wave wstart, deg -> dis, Xs = dis*x ----------------

__global__ void build_stream_kernel(const unsigned* __restrict__ binned, const int* __restrict__ bbase,
                                    const float* __restrict__ x, float* __restrict__ dis_g,
                                    float* __restrict__ Xs, unsigned* __restrict__ col3,
                                    unsigned short* __restrict__ cnt16, int* __restrict__ wstart,
                                    int n) {
    __shared__ int ck[NKEYP];
    __shared__ int wsum[4];
    const int b = blockIdx.x;
    const int node_base = b * NBK;
    const int tid = threadIdx.x;
    for (int i = tid; i < NKEYP; i += 256) ck[i] = 0;
    __syncthreads();
    const int e0 = bbase[b], e1 = bbase[b + 1];
    for (int e = e0 + tid; e < e1; e += 256) {
        unsigned v = binned[e];
        int dloc = v >> 24;
        int tt = (int)((v & 0xFFFFFFu) >> TSHIFT);
        atomicAdd(&ck[(dloc / NPW) * 400 + tt * 25 + (dloc % NPW)], 1);
    }
    __syncthreads();
    // degrees -> dis, Xs
    if (tid < NBK) {
        int node = node_base + tid;
        if (node < n) {
            int wl = tid / NPW, k = tid % NPW;
            int deg = 0;
            #pragma unroll
            for (int tt = 0; tt < NT; ++tt) deg += ck[wl * 400 + tt * 25 + k];
            float d = rsqrtf((float)deg + 1.0f);
            dis_g[node] = d;
            float4 xv = *(const float4*)&x[node * 4];
            *(float4*)&Xs[node * 4] = make_float4(d * xv.x, d * xv.y, d * xv.z, d * xv.w);
        }
    }
    // per-(wave,tile) totals
    if (tid < 128) {
        int wl = tid >> 4, tt = tid & 15;
        int s = 0;
        #pragma unroll
        for (int sl = 0; sl < NPW; ++sl) s += ck[wl * 400 + tt * 25 + sl];
        cnt16[(size_t)(b * 8 + wl) * NT + tt] = (unsigned short)s;
    }
    __syncthreads();
    // exclusive scan over 3328 keys (13/thread) -> absolute col3 offsets
    const int base_i = tid * 13;
    int lsum = 0;
    #pragma unroll
    for (int j = 0; j < 13; ++j) lsum += ck[base_i + j];
    const int lane = tid & 63, wid = tid >> 6;
    int s = lsum;
    #pragma unroll
    for (int off = 1; off < 64; off <<= 1) {
        int t = __shfl_up(s, off);
        if (lane >= off) s += t;
    }
    if (lane == 63) wsum[wid] = s;
    __syncthreads();
    int woff = 0;
    for (int w = 0; w < wid; ++w) woff += wsum[w];
    int run = e0 + woff + s - lsum;
    #pragma unroll
    for (int j = 0; j < 13; ++j) { int c = ck[base_i + j]; ck[base_i + j] = run; run += c; }
    __syncthreads();
    if (tid < 8) wstart[b * 8 + tid] = ck[tid * 400];
    __syncthreads();
    // scatter: col3 = (slot<<24) | src, ordered by (wave, tile, slot)
    for (int e = e0 + tid; e < e1; e += 256) {
        unsigned v = binned[e];
        int dloc = v >> 24;
        unsigned srcv = v & 0xFFFFFFu;
        int tt = (int)(srcv >> TSHIFT);
        int p = atomicAdd(&ck[(dloc / NPW) * 400 + tt * 25 + (dloc % NPW)], 1);
        col3[p] = ((unsigned)(dloc % NPW) << 24) | srcv;
    }
}

// ---------------- phase-aligned aggregation, 1 DS-op per edge-group ----------------
// 1000 blocks x 4 waves, all resident. Wave owns NPW=25 nodes, acc[25][F] wave-private LDS.
// EPG=64/F edges per instruction group: lanes split into EPG groups of F lanes; group g
// handles edge j+g (edge word loaded directly - uniform/coalesced, no shfl). Accumulate
// via ds_add_f32 (atomicAdd, no return) - deterministic program order per (node,f).
// Chip-wide tile phases align -> gathers hit a 2MB L2-resident slice per phase.

template <int F, bool RELU, bool BIAS, int UNR>
__global__ __launch_bounds__(256, 4)
void agg_phase_kernel(const float* __restrict__ t, const unsigned* __restrict__ col3,
                      const unsigned short* __restrict__ cnt16, const int* __restrict__ wstart,
                      const float* __restrict__ dis, const float* __restrict__ bias,
                      float* __restrict__ out, int n, int nwave) {
    constexpr int EPG = 64 / F;
    __shared__ float accs[4][NPW * F];
    const int tid = threadIdx.x;
    const int wl = tid >> 6, lane = tid & 63;
    float* acc = accs[wl];
    for (int i = lane; i < NPW * F; i += 64) acc[i] = 0.0f;
    const int gw = blockIdx.x * 4 + wl;
    if (gw >= nwave) return;
    const int grp = lane / F;
    const int fl = lane & (F - 1);
    int cur = __builtin_amdgcn_readfirstlane(wstart[gw]);
    for (int tp = 0; tp < NT; ++tp) {
        const int cnt = __builtin_amdgcn_readfirstlane((int)cnt16[(size_t)gw * NT + tp]);
        const int jmain = cnt & ~(UNR * EPG - 1);
        int j = 0;
        for (; j < jmain; j += UNR * EPG) {
            #pragma unroll
            for (int u = 0; u < UNR; ++u) {
                const unsigned v = col3[cur + j + u * EPG + grp];
                const float xv = t[(size_t)(v & 0xFFFFFFu) * F + fl];
                atomicAdd(&acc[(v >> 24) * F + fl], xv);
            }
        }
        for (int idx = j + grp; idx < cnt; idx += EPG) {
            const unsigned v = col3[cur + idx];
            const float xv = t[(size_t)(v & 0xFFFFFFu) * F + fl];
            atomicAdd(&acc[(v >> 24) * F + fl], xv);
        }
        cur += cnt;
    }
    // epilogue: out = [relu]( dis_i * (acc + t_self) + [bias] )
    const int nodeb = gw * NPW;
    const float bv = BIAS ? bias[fl] : 0.0f;
    for (int k = 0; k < NPW; ++k) {
        int i = nodeb + k;
        if (i < n && lane < F) {
            float d = dis[i];
            float r = d * (acc[k * F + fl] + t[(size_t)i * F + fl]) + bv;
            if (RELU) r = fmaxf(r, 0.0f);
            out[(size_t)i * F + fl] = r;
        }
    }
}

// ---------------- fused layer-1 transform + layer-2 pre-transform ----------------
// T[i] = dis[i] * ( relu(aggX[i] @ W1 + b1) @ W2 )

__global__ void fused_l1_kernel(const float* __restrict__ aggX, const float* __restrict__ W1,
                                const float* __restrict__ b1, const float* __restrict__ W2,
                                const float* __restrict__ dis, float* __restrict__ t, int n) {
    __shared__ float W1s[256];
    __shared__ float b1s[64];
    __shared__ float Wt[64 * TPAD];
    __shared__ float Hs[64 * TPAD];
    const int tid = threadIdx.x;
    const int base = blockIdx.x * 64;
    if (tid < 256) W1s[tid] = W1[tid];
    if (tid < 64) b1s[tid] = b1[tid];
    for (int idx = tid; idx < 4096; idx += 256) {
        int k = idx >> 6, f = idx & 63;
        Wt[f * TPAD + k] = W2[idx];
    }
    __syncthreads();
    for (int idx = tid; idx < 4096; idx += 256) {
        int nn = idx >> 6, k = idx & 63;
        int node = base + nn;
        float v = 0.0f;
        if (node < n) {
            float4 a = *(const float4*)&aggX[node * 4];
            v = fmaxf(a.x * W1s[k] + a.y * W1s[64 + k] + a.z * W1s[128 + k] + a.w * W1s[192 + k]
                      + b1s[k], 0.0f);
        }
        Hs[nn * TPAD + k] = v;
    }
    __syncthreads();
    const int tf = tid & 15;
    const int tn = tid >> 4;
    float acc[4][4] = {};
    for (int k = 0; k < 64; k += 4) {
        float4 w4[4], h4[4];
        #pragma unroll
        for (int ff = 0; ff < 4; ++ff) w4[ff] = *(const float4*)&Wt[(tf * 4 + ff) * TPAD + k];
        #pragma unroll
        for (int nn = 0; nn < 4; ++nn) h4[nn] = *(const float4*)&Hs[(tn * 4 + nn) * TPAD + k];
        #pragma unroll
        for (int nn = 0; nn < 4; ++nn)
            #pragma unroll
            for (int ff = 0; ff < 4; ++ff)
                acc[nn][ff] += h4[nn].x * w4[ff].x + h4[nn].y * w4[ff].y +
                               h4[nn].z * w4[ff].z + h4[nn].w * w4[ff].w;
    }
    #pragma unroll
    for (int nn = 0; nn < 4; ++nn) {
        int node = base + tn * 4 + nn;
        if (node < n) {
            float d = dis[node];
            float4 o = make_float4(d * acc[nn][0], d * acc[nn][1], d * acc[nn][2], d * acc[nn][3]);
            *(float4*)&t[node * 64 + tf * 4] = o;
        }
    }
}

// ---------------- W3 transform: T32[i] = dis[i] * (H[i] @ W3) ----------------

__global__ void transform64_32_kernel(const float* __restrict__ h, const float* __restrict__ W,
                                      const float* __restrict__ dis, float* __restrict__ t, int n) {
    __shared__ float Wt[32 * TPAD];
    __shared__ float Hs[128 * TPAD];
    const int tid = threadIdx.x;
    const int base = blockIdx.x * 128;
    for (int idx = tid; idx < 2048; idx += 256) {
        int k = idx >> 5, f = idx & 31;
        Wt[f * TPAD + k] = W[idx];
    }
    for (int idx = tid; idx < 8192; idx += 256) {
        int nn = idx >> 6, k = idx & 63;
        int node = base + nn;
        Hs[nn * TPAD + k] = (node < n) ? h[node * 64 + k] : 0.0f;
    }
    __syncthreads();
    const int tf = tid & 7;
    const int tn = tid >> 3;
    float acc[4][4] = {};
    for (int k = 0; k < 64; k += 4) {
        float4 w4[4], h4[4];
        #pragma unroll
        for (int ff = 0; ff < 4; ++ff) w4[ff] = *(const float4*)&Wt[(tf * 4 + ff) * TPAD + k];
        #pragma unroll
        for (int nn = 0; nn < 4; ++nn) h4[nn] = *(const float4*)&Hs[(tn * 4 + nn) * TPAD + k];
        #pragma unroll
        for (int nn = 0; nn < 4; ++nn)
            #pragma unroll
            for (int ff = 0; ff < 4; ++ff)
                acc[nn][ff] += h4[nn].x * w4[ff].x + h4[nn].y * w4[ff].y +
                               h4[nn].z * w4[ff].z + h4[nn].w * w4[ff].w;
    }
    #pragma unroll
    for (int nn = 0; nn < 4; ++nn) {
        int node = base + tn * 4 + nn;
        if (node < n) {
            float d = dis[node];
            float4 o = make_float4(d * acc[nn][0], d * acc[nn][1], d * acc[nn][2], d * acc[nn][3]);
            *(float4*)&t[node * 32 + tf * 4] = o;
        }
    }
}

// ---------------- readout ----------------

__device__ __forceinline__ unsigned mapf(float v) {
    unsigned u = __float_as_uint(v);
    return u ^ ((u & 0x80000000u) ? 0xFFFFFFFFu : 0x80000000u);
}

#define MAPPED_NEG_INF 0x007FFFFFu

__global__ void init_readout_kernel(float* __restrict__ gsum, unsigned* __restrict__ gmax,
                                    int* __restrict__ gcnt) {
    int idx = blockIdx.x * blockDim.x + threadIdx.x;
    if (idx < N_GRAPHS * 32) { gsum[idx] = 0.0f; gmax[idx] = MAPPED_NEG_INF; }
    if (idx < N_GRAPHS) gcnt[idx] = 0;
}

#define R_CHUNK 512
__global__ void readout_kernel(const float* __restrict__ emb, const int* __restrict__ batch,
                               float* __restrict__ gsum, unsigned* __restrict__ gmax,
                               int* __restrict__ gcnt, int n) {
    __shared__ float ssum[N_GRAPHS * 32];
    __shared__ unsigned smax[N_GRAPHS * 32];
    __shared__ int scnt[N_GRAPHS];
    const int tid = threadIdx.x;
    for (int idx = tid; idx < N_GRAPHS * 32; idx += 256) { ssum[idx] = 0.0f; smax[idx] = MAPPED_NEG_INF; }
    if (tid < N_GRAPHS) scnt[tid] = 0;
    __syncthreads();
    const int lane = tid & 31, grp = tid >> 5;
    const int start = blockIdx.x * R_CHUNK;
    const int end = min(start + R_CHUNK, n);
    for (int i = start + grp; i < end; i += 8) {
        int g = batch[i];
        float v = emb[i * 32 + lane];
        atomicAdd(&ssum[g * 32 + lane], v);
        atomicMax(&smax[g * 32 + lane], mapf(v));
        if (lane == 0) atomicAdd(&scnt[g], 1);
    }
    __syncthreads();
    for (int idx = tid; idx < N_GRAPHS * 32; idx += 256) {
        int g = idx >> 5;
        if (scnt[g] > 0) {
            atomicAdd(&gsum[idx], ssum[idx]);
            atomicMax(&gmax[idx], smax[idx]);
        }
    }
    if (tid < N_GRAPHS && scnt[tid] > 0) atomicAdd(&gcnt[tid], scnt[tid]);
}

__global__ void finalize_kernel(const float* __restrict__ gsum, const unsigned* __restrict__ gmax,
                                const int* __restrict__ gcnt, float* __restrict__ out) {
    int idx = blockIdx.x * blockDim.x + threadIdx.x;
    if (idx >= N_GRAPHS * 32) return;
    int g = idx >> 5, f = idx & 31;
    float c = fmaxf((float)gcnt[g], 1.0f);
    out[g * 64 + f] = gsum[idx] / c;
    unsigned u = gmax[idx];
    unsigned bits = (u & 0x80000000u) ? (u ^ 0x80000000u) : ~u;
    out[g * 64 + 32 + f] = __uint_as_float(bits);
}

// ---------------- launch ----------------

extern "C" void kernel_launch(void* const* d_in, const int* in_sizes, int n_in,
                              void* d_out, int out_size, void* d_ws, size_t ws_size,
                              hipStream_t stream) {
    const float* x  = (const float*)d_in[0];
    const float* W1 = (const float*)d_in[1];
    const float* b1 = (const float*)d_in[2];
    const float* W2 = (const float*)d_in[3];
    const float* b2 = (const float*)d_in[4];
    const float* W3 = (const float*)d_in[5];
    const float* b3 = (const float*)d_in[6];
    const int* edge_index = (const int*)d_in[7];
    const int* batch = (const int*)d_in[8];
    float* out = (float*)d_out;

    const int N = in_sizes[0] / 4;
    const int E = in_sizes[7] / 2;
    const int* src = edge_index;
    const int* dst = edge_index + E;
    const int nbuck = (N + NBK - 1) / NBK;   // 500
    const int nwave = nbuck * 8;             // 4000 (wave = 25 nodes)
    const int gagg = (nwave + 3) / 4;        // 1000 blocks, all resident

    // workspace carve-up (256B aligned)
    char* p = (char*)d_ws;
    auto alloc = [&](size_t bytes) { void* r = (void*)p; p += (bytes + 255) & ~(size_t)255; return r; };
    float*          dis    = (float*)alloc((size_t)N * 4);
    unsigned*       col3   = (unsigned*)alloc((size_t)E * 4);
    unsigned short* cnt16  = (unsigned short*)alloc((size_t)nwave * NT * 2);
    int*            wstart = (int*)alloc((size_t)nwave * 4);
    float*          T      = (float*)alloc((size_t)N * 64 * 4);
    float*          H      = (float*)alloc((size_t)N * 64 * 4);
    float*          T32    = (float*)alloc((size_t)N * 32 * 4);
    int*            bcnt   = (int*)alloc((size_t)512 * 4);
    int*            bbase  = (int*)alloc((size_t)513 * 4);
    int*            bcur   = (int*)alloc((size_t)512 * 4);
    float*          gsum   = (float*)alloc((size_t)N_GRAPHS * 32 * 4);
    unsigned*       gmax   = (unsigned*)alloc((size_t)N_GRAPHS * 32 * 4);
    int*            gcnt   = (int*)alloc((size_t)N_GRAPHS * 4);
    // aliases (lifetimes disjoint, stream-ordered):
    unsigned* binned = (unsigned*)T;           // consumed by build before fused_l1 writes T
    float*    Xs     = H;                      // dead before agg<64> writes H
    float*    aggX   = H + (size_t)N * 4;      // dead before agg<64> writes H
    float*    H32    = T;                      // written after T dead (post transform64_32)
    (void)ws_size; (void)n_in; (void)out_size;

    // CSR build: bucket-binned scatter, then per-bucket (wave,tile,slot) sort
    hipMemsetAsync(bcnt, 0, 512 * 4, stream);
    bucket_hist_kernel<<<(E + EBH - 1) / EBH, 256, 0, stream>>>(dst, bcnt, E, nbuck);
    bucket_scan_kernel<<<1, 512, 0, stream>>>(bcnt, bbase, bcur, nbuck);
    binscatter_kernel<<<(E + EBC - 1) / EBC, 256, 0, stream>>>(src, dst, bcur, binned, E, nbuck);
    build_stream_kernel<<<nbuck, 256, 0, stream>>>(binned, bbase, x, dis, Xs, col3, cnt16, wstart, N);

    // layer 1: phase-aligned aggregate Xs (4-dim) -> aggX, then fused transform -> T
    agg_phase_kernel<4, false, false, 4><<<gagg, 256, 0, stream>>>(Xs, col3, cnt16, wstart, dis, b1, aggX, N, nwave);
    fused_l1_kernel<<<(N + 63) / 64, 256, 0, stream>>>(aggX, W1, b1, W2, dis, T, N);
    // layer 2: phase-aligned aggregate T (64-dim) -> H = relu(dis*(sum+self)+b2)
    agg_phase_kernel<64, true, true, 8><<<gagg, 256, 0, stream>>>(T, col3, cnt16, wstart, dis, b2, H, N, nwave);
    // W3: T32 = dis * (H @ W3)
    transform64_32_kernel<<<(N + 127) / 128, 256, 0, stream>>>(H, W3, dis, T32, N);
    // layer 3: phase-aligned aggregate T32 (32-dim) -> H32 = dis*(sum+self)+b3
    agg_phase_kernel<32, false, true, 8><<<gagg, 256, 0, stream>>>(T32, col3, cnt16, wstart, dis, b3, H32, N, nwave);

    // readout
    init_readout_kernel<<<(N_GRAPHS * 32 + 255) / 256, 256, 0, stream>>>(gsum, gmax, gcnt);
    readout_kernel<<<(N + R_CHUNK - 1) / R_CHUNK, 256, 0, stream>>>(H32, batch, gsum, gmax, gcnt, N);
    finalize_kernel<<<(N_GRAPHS * 32 + 255) / 256, 256, 0, stream>>>(gsum, gmax, gcnt, out);
}